// Round 9
// baseline (314.196 us; speedup 1.0000x reference)
//
#include <hip/hip_runtime.h>

// Batched expm of symmetrized 64x64 fp32 matrices via scaling-and-squaring
// (s=4, degree-11 Taylor, Paterson-Stockmeyer chunk-2), matmuls on the MFMA
// pipe via fp16 2-way-split emulation of fp32:
//   x = hi + lo/2048 (hi RTZ-rounded fp16, lo fp16 of residual*2048)
//   A*B ~= Ah*Bh + (Ah*Bl' + Al'*Bh)/2048        (6 MFMAs per 16x16 tile)
// All operands are symmetric (polynomials in T):
//   - B-fragment == A-fragment read pattern (contiguous ds_read_b128)
//   - intermediate C tiles written TRANSPOSED to LDS => contiguous writes
// fp16 planes [64][64] XOR-swizzled: byte ^= (row&7)<<4 (bank-conflict fix).
// Range: last Taylor stage folds *0.5 => Q=P/2; out = Q^16 * 65536.
//
// R9: 512-thread blocks (8 waves, 2 C-tiles each). LDS 48KB -> still 3
// blocks/CU but 24 waves/CU = 6 waves/SIMD (was 3) to overlap the VALU
// split/repack pipe with the MFMA pipe across waves. T2 fragments are
// re-read from LDS each Horner stage (keeps VGPR under the 85 cap of
// __launch_bounds__(512,6); caching them risks spills).

typedef _Float16 half2v __attribute__((ext_vector_type(2)));
typedef _Float16 half4v __attribute__((ext_vector_type(4)));
typedef _Float16 half8v __attribute__((ext_vector_type(8)));
typedef float f32x4 __attribute__((ext_vector_type(4)));

constexpr int N = 64;

__device__ __forceinline__ void split2(float v0, float v1, half2v& h, half2v& l) {
    h = __builtin_bit_cast(half2v, __builtin_amdgcn_cvt_pkrtz(v0, v1));
    l = __builtin_bit_cast(half2v, __builtin_amdgcn_cvt_pkrtz((v0 - (float)h[0]) * 2048.0f,
                                                              (v1 - (float)h[1]) * 2048.0f));
}

__device__ __forceinline__ void split4(const float* v, half4v& h, half4v& l) {
    half2v h01, l01, h23, l23;
    split2(v[0], v[1], h01, l01);
    split2(v[2], v[3], h23, l23);
    h[0] = h01[0]; h[1] = h01[1]; h[2] = h23[0]; h[3] = h23[1];
    l[0] = l01[0]; l[1] = l01[1]; l[2] = l23[0]; l[3] = l23[1];
}

__device__ __forceinline__ void split8(const float* v, half8v& h, half8v& l) {
    half2v hh[4], ll[4];
    #pragma unroll
    for (int q = 0; q < 4; ++q) split2(v[2 * q], v[2 * q + 1], hh[q], ll[q]);
    #pragma unroll
    for (int q = 0; q < 4; ++q) {
        h[2 * q] = hh[q][0]; h[2 * q + 1] = hh[q][1];
        l[2 * q] = ll[q][0]; l[2 * q + 1] = ll[q][1];
    }
}

__device__ __forceinline__ int swz(int row, int colbyte) {
    return (row * 128 + colbyte) ^ ((row & 7) << 4);
}

// A-frag (and, by symmetry, B-frag): lane reads M[tile*16 + lane%16][k0..k0+7],
// k0 = ks*32 + (lane/16)*8  -> one 16B ds_read_b128 (swizzled).
__device__ __forceinline__ half8v frag16(const char* p, int tile, int ks, int lane) {
    const int row = tile * 16 + (lane & 15);
    const int cb = (ks * 32 + ((lane >> 4) << 3)) * 2;
    return *reinterpret_cast<const half8v*>(p + swz(row, cb));
}

// 6-MFMA split product over K=64 (2 ksteps) for one 16x16 C tile.
__device__ __forceinline__ f32x4 mm_split(const half8v* ah, const half8v* al,
                                          const half8v* bh, const half8v* bl) {
    f32x4 c = {0.f, 0.f, 0.f, 0.f};
    c = __builtin_amdgcn_mfma_f32_16x16x32_f16(al[0], bh[0], c, 0, 0, 0);  // cross (x2^11)
    c = __builtin_amdgcn_mfma_f32_16x16x32_f16(al[1], bh[1], c, 0, 0, 0);
    c = __builtin_amdgcn_mfma_f32_16x16x32_f16(ah[0], bl[0], c, 0, 0, 0);
    c = __builtin_amdgcn_mfma_f32_16x16x32_f16(ah[1], bl[1], c, 0, 0, 0);
    #pragma unroll
    for (int e = 0; e < 4; ++e) c[e] *= (1.0f / 2048.0f);                  // -> 1
    c = __builtin_amdgcn_mfma_f32_16x16x32_f16(ah[0], bh[0], c, 0, 0, 0);  // hi*hi
    c = __builtin_amdgcn_mfma_f32_16x16x32_f16(ah[1], bh[1], c, 0, 0, 0);
    return c;
}

__global__ __launch_bounds__(512, 6) void expm64_kernel(const float* __restrict__ X,
                                                        float* __restrict__ out) {
    __shared__ alignas(16) char lds[49152];
    char* Th = lds;            // T hi plane   (8 KB each)
    char* Tl = lds + 8192;     // T lo
    char* Ph = lds + 16384;    // P hi
    char* Pl = lds + 24576;    // P lo
    char* Qh = lds + 32768;    // T2 hi
    char* Ql = lds + 40960;    // T2 lo
    float* Xs = reinterpret_cast<float*>(lds + 16384);  // fp32 X staging over Ph/Pl

    const int t = threadIdx.x;
    const int lane = t & 63;
    const int wv = t >> 6;          // wave 0..7
    const int wr = wv >> 1;         // row-tile 0..3
    const int wc0 = (wv & 1) << 1;  // first col-tile (0 or 2)
    const size_t base = (size_t)blockIdx.x * (N * N);

    // ---- load X (fp32) coalesced into staging: 2 float4 per thread ----
    {
        const float4* src = reinterpret_cast<const float4*>(X + base);
        float4* dst = reinterpret_cast<float4*>(Xs);
        dst[t] = src[t];
        dst[t + 512] = src[t + 512];
    }
    __syncthreads();

    const int r = t >> 3;          // row 0..63
    const int c0 = (t & 7) << 3;   // col base 0,8,...,56

    // ---- T = (X + X^T)/32, split -> Th/Tl; keep fp32 strip in regs ----
    float tv[8];
    {
        #pragma unroll
        for (int j = 0; j < 8; ++j)
            tv[j] = (Xs[r * 64 + c0 + j] + Xs[(c0 + j) * 64 + r]) * (1.0f / 32.0f);
        half8v h, l;
        split8(tv, h, l);
        *reinterpret_cast<half8v*>(Th + swz(r, c0 * 2)) = h;
        *reinterpret_cast<half8v*>(Tl + swz(r, c0 * 2)) = l;
    }
    __syncthreads();   // X consumed, T planes complete

    // ---- P0 = c10*I + c11*T -> Ph/Pl (overwrites X staging) ----
    {
        const float c10 = 2.755731922398589e-07f;   // 1/10!
        const float c11 = 2.505210838544172e-08f;   // 1/11!
        float v[8];
        #pragma unroll
        for (int j = 0; j < 8; ++j)
            v[j] = c11 * tv[j] + ((r == c0 + j) ? c10 : 0.0f);
        half8v h, l;
        split8(v, h, l);
        *reinterpret_cast<half8v*>(Ph + swz(r, c0 * 2)) = h;
        *reinterpret_cast<half8v*>(Pl + swz(r, c0 * 2)) = l;
    }
    __syncthreads();

    // ---- stage 1: T2 = T*T -> Qh/Ql (write arena != read arena: 1 barrier) ----
    {
        half8v ah[2], al[2], bh[2][2], bl[2][2];
        #pragma unroll
        for (int ks = 0; ks < 2; ++ks) {
            ah[ks] = frag16(Th, wr, ks, lane);
            al[ks] = frag16(Tl, wr, ks, lane);
        }
        #pragma unroll
        for (int cb = 0; cb < 2; ++cb)
            #pragma unroll
            for (int ks = 0; ks < 2; ++ks) {
                bh[cb][ks] = frag16(Th, wc0 + cb, ks, lane);
                bl[cb][ks] = frag16(Tl, wc0 + cb, ks, lane);
            }
        #pragma unroll
        for (int cb = 0; cb < 2; ++cb) {
            f32x4 acc = mm_split(ah, al, bh[cb], bl[cb]);
            const int rowp = (wc0 + cb) * 16 + (lane & 15);   // transposed
            const int colp = wr * 16 + ((lane >> 4) << 2);
            float v[4] = { acc[0], acc[1], acc[2], acc[3] };
            half4v h, l;
            split4(v, h, l);
            *reinterpret_cast<half4v*>(Qh + swz(rowp, colp * 2)) = h;
            *reinterpret_cast<half4v*>(Ql + swz(rowp, colp * 2)) = l;
        }
    }
    __syncthreads();

    // ---- 5 Horner stages: P = P*T2 + ce[s]*I + co[s]*T ----
    {
        const float ce[5] = { 2.48015873015873e-05f, 1.388888888888889e-03f,
                              4.1666666666666664e-02f, 0.5f, 1.0f };
        const float co[5] = { 2.7557319223985893e-06f, 1.984126984126984e-04f,
                              8.333333333333333e-03f, 1.6666666666666666e-01f, 1.0f };
        #pragma unroll
        for (int s = 0; s < 5; ++s) {
            half8v ah[2], al[2], bh[2][2], bl[2][2];
            #pragma unroll
            for (int ks = 0; ks < 2; ++ks) {
                ah[ks] = frag16(Ph, wr, ks, lane);
                al[ks] = frag16(Pl, wr, ks, lane);
            }
            #pragma unroll
            for (int cb = 0; cb < 2; ++cb)
                #pragma unroll
                for (int ks = 0; ks < 2; ++ks) {
                    bh[cb][ks] = frag16(Qh, wc0 + cb, ks, lane);   // T2 frags (re-read)
                    bl[cb][ks] = frag16(Ql, wc0 + cb, ks, lane);
                }
            f32x4 acc[2];
            #pragma unroll
            for (int cb = 0; cb < 2; ++cb)
                acc[cb] = mm_split(ah, al, bh[cb], bl[cb]);
            __syncthreads();   // all waves done reading Ph/Pl
            const float fin = (s == 4) ? 0.5f : 1.0f;   // fold Q = P/2 into last stage
            #pragma unroll
            for (int cb = 0; cb < 2; ++cb) {
                const int rowp = (wc0 + cb) * 16 + (lane & 15);
                const int colp = wr * 16 + ((lane >> 4) << 2);
                const half4v th = *reinterpret_cast<const half4v*>(Th + swz(rowp, colp * 2));
                const half4v tl = *reinterpret_cast<const half4v*>(Tl + swz(rowp, colp * 2));
                float v[4];
                #pragma unroll
                for (int e = 0; e < 4; ++e) {
                    const int grow = colp + e;        // element's C row
                    const int gcol = rowp;            // element's C col
                    const float tval = (float)th[e] + (float)tl[e] * (1.0f / 2048.0f);
                    v[e] = (acc[cb][e] + co[s] * tval
                            + ((grow == gcol) ? ce[s] : 0.0f)) * fin;
                }
                half4v h, l;
                split4(v, h, l);
                *reinterpret_cast<half4v*>(Ph + swz(rowp, colp * 2)) = h;
                *reinterpret_cast<half4v*>(Pl + swz(rowp, colp * 2)) = l;
            }
            __syncthreads();
        }
    }

    // ---- 4 squarings: Q = Q*Q; last one stores f32 directly to global ----
    #pragma unroll
    for (int s = 0; s < 4; ++s) {
        half8v ah[2], al[2], bh[2][2], bl[2][2];
        #pragma unroll
        for (int ks = 0; ks < 2; ++ks) {
            ah[ks] = frag16(Ph, wr, ks, lane);
            al[ks] = frag16(Pl, wr, ks, lane);
        }
        #pragma unroll
        for (int cb = 0; cb < 2; ++cb)
            #pragma unroll
            for (int ks = 0; ks < 2; ++ks) {
                bh[cb][ks] = frag16(Ph, wc0 + cb, ks, lane);
                bl[cb][ks] = frag16(Pl, wc0 + cb, ks, lane);
            }
        f32x4 acc[2];
        #pragma unroll
        for (int cb = 0; cb < 2; ++cb)
            acc[cb] = mm_split(ah, al, bh[cb], bl[cb]);
        if (s < 3) {
            __syncthreads();
            #pragma unroll
            for (int cb = 0; cb < 2; ++cb) {
                const int rowp = (wc0 + cb) * 16 + (lane & 15);
                const int colp = wr * 16 + ((lane >> 4) << 2);
                float v[4] = { acc[cb][0], acc[cb][1], acc[cb][2], acc[cb][3] };
                half4v h, l;
                split4(v, h, l);
                *reinterpret_cast<half4v*>(Ph + swz(rowp, colp * 2)) = h;
                *reinterpret_cast<half4v*>(Pl + swz(rowp, colp * 2)) = l;
            }
            __syncthreads();
        } else {
            // direct untransposed store: C[row][col], row from A-tile, col from B-tile.
            float* o = out + base;
            #pragma unroll
            for (int cb = 0; cb < 2; ++cb) {
                const int row0 = wr * 16 + ((lane >> 4) << 2);
                const int col  = (wc0 + cb) * 16 + (lane & 15);
                #pragma unroll
                for (int e = 0; e < 4; ++e)
                    o[(row0 + e) * 64 + col] = acc[cb][e] * 65536.0f;
            }
        }
    }
}

extern "C" void kernel_launch(void* const* d_in, const int* in_sizes, int n_in,
                              void* d_out, int out_size, void* d_ws, size_t ws_size,
                              hipStream_t stream) {
    const float* X = (const float*)d_in[0];
    float* out = (float*)d_out;
    const int batch = in_sizes[0] / (N * N);   // 8192
    expm64_kernel<<<dim3(batch), dim3(512), 0, stream>>>(X, out);
}